// Round 3
// baseline (201.846 us; speedup 1.0000x reference)
//
#include <hip/hip_runtime.h>
#include <math.h>

#define C_CH 256
#define T_LEN 4096

// d_ws layout: per channel c, 32 floats:
//   [0..26] folded 9-tap weights w[r][k] (r*9+k), [27] Beff, [28..31] pad
// then at float offset 8192: int completion counter (zeroed by fold_kernel).

// ---------------------------------------------------------------------------
// K0: fold conv weights once + zero the tail counter. 1 block, 256 threads.
// ---------------------------------------------------------------------------
template <int K>
__device__ inline void fold_bundle(const float* __restrict__ wp,
                                   const float* __restrict__ bp,
                                   const float* __restrict__ wred6,
                                   int p0, float* __restrict__ w9, float& bacc)
{
    const int off = (9 - K) >> 1;
    #pragma unroll
    for (int k = 0; k < 9; ++k) w9[k] = 0.0f;
    #pragma unroll
    for (int j = 0; j < 6; ++j) {
        const float wr = wred6[j];
        bacc += wr * bp[p0 + j];
        #pragma unroll
        for (int k = 0; k < K; ++k)
            w9[off + k] += wr * wp[(p0 + j) * K + k];
    }
}

__global__ __launch_bounds__(256) void fold_kernel(
    const float* __restrict__ w3, const float* __restrict__ b3,
    const float* __restrict__ w5, const float* __restrict__ b5,
    const float* __restrict__ w9, const float* __restrict__ b9,
    const float* __restrict__ w_red, const float* __restrict__ b_red,
    float* __restrict__ ws)
{
    const int c = threadIdx.x;
    float wf[3][9];
    float bacc = 0.0f;
    #pragma unroll
    for (int r = 0; r < 3; ++r) {
        const int q0 = 18 * c + 6 * r;
        const float* wred6 = w_red + c * 18 + 6 * r;
        if (q0 < 1536)      fold_bundle<3>(w3, b3, wred6, q0,        wf[r], bacc);
        else if (q0 < 3072) fold_bundle<5>(w5, b5, wred6, q0 - 1536, wf[r], bacc);
        else                fold_bundle<9>(w9, b9, wred6, q0 - 3072, wf[r], bacc);
    }
    float* o = ws + c * 32;
    #pragma unroll
    for (int r = 0; r < 3; ++r)
        #pragma unroll
        for (int k = 0; k < 9; ++k) o[r * 9 + k] = wf[r][k];
    o[27] = b_red[c] + bacc;
    o[28] = 0.0f; o[29] = 0.0f; o[30] = 0.0f; o[31] = 0.0f;
    if (c == 0) ((int*)ws)[8192] = 0;   // tail counter
}

// ---------------------------------------------------------------------------
// K1: fused drive + LIF scan + latency/act; last block runs the MLP tail.
// One block per (b, c); 256 threads x 16 t-steps each.
// ---------------------------------------------------------------------------
__global__ __launch_bounds__(256) void fused_kernel(
    const float* __restrict__ x, const float* __restrict__ ws,
    const float* __restrict__ latency_scale,
    const float* __restrict__ og, const float* __restrict__ bias,
    const float* __restrict__ W1, const float* __restrict__ b1,
    const float* __restrict__ W2, const float* __restrict__ b2,
    float* __restrict__ out_pred, float* __restrict__ out_lat,
    float* __restrict__ out_act, int* __restrict__ counter)
{
    const int blk  = blockIdx.x;       // b*256 + c
    const int b    = blk >> 8;
    const int c    = blk & 255;
    const int tid  = threadIdx.x;
    const int lane = tid & 63;
    const int wv   = tid >> 6;

    __shared__ float sWaveTot[4];
    __shared__ float sCarry[4];
    __shared__ int   sMin[4];
    __shared__ int   sIsLast;

    // --- x loads: src channels computed arithmetically, issue immediately ---
    const int base = 16 * tid - 4;               // window [t-4, t+4), t in [16*tid, +16)
    float xa[3][24];
    #pragma unroll
    for (int r = 0; r < 3; ++r) {
        const int q      = 18 * c + 6 * r;
        const int region = (q >= 1536) + (q >= 3072);
        const int srcc   = 3 * c + r - (region << 8);
        const float* xr  = x + ((size_t)b * C_CH + srcc) * T_LEN;
        if (tid > 0 && tid < 255) {
            const float4* p = (const float4*)(xr + base);  // base % 4 == 0 -> aligned
            #pragma unroll
            for (int v = 0; v < 6; ++v) {
                float4 q4 = p[v];
                xa[r][4 * v + 0] = q4.x; xa[r][4 * v + 1] = q4.y;
                xa[r][4 * v + 2] = q4.z; xa[r][4 * v + 3] = q4.w;
            }
        } else {
            #pragma unroll
            for (int e = 0; e < 24; ++e) {
                const int t = base + e;
                xa[r][e] = (t >= 0 && t < T_LEN) ? xr[t] : 0.0f;  // conv zero-pad
            }
        }
    }

    // --- folded weights: block-uniform address -> scalar loads, no LDS ---
    const float* wc = ws + c * 32;
    const float Beff = wc[27];
    float d[16];
    #pragma unroll
    for (int tt = 0; tt < 16; ++tt) d[tt] = Beff;
    #pragma unroll
    for (int r = 0; r < 3; ++r) {
        #pragma unroll
        for (int k = 0; k < 9; ++k) {
            const float wk = wc[r * 9 + k];
            #pragma unroll
            for (int tt = 0; tt < 16; ++tt)
                d[tt] = fmaf(wk, xa[r][tt + k], d[tt]);
        }
    }

    const float A   = (float)0.8187307530779818;          // exp(-1/5), fp32
    const float OMA = (float)(1.0 - 0.8187307530779818);  // matches ref rounding

    // --- chunk-local scan: V after 16 steps from 0 ---
    float S = 0.0f;
    #pragma unroll
    for (int tt = 0; tt < 16; ++tt) S = A * S + OMA * d[tt];

    // --- wave-level weighted inclusive scan (per-chunk decay A^16) ---
    const float Fp[6] = {
        (float)4.0762203978366215e-02,  // A^16  = e^-3.2
        (float)1.6615572731739337e-03,  // A^32
        (float)2.7607725720371943e-06,  // A^64
        (float)7.6218649302532563e-12,  // A^128
        (float)5.8092835977683129e-23,  // A^256
        (float)3.3744728758705166e-45   // A^512 (denormal)
    };
    float cinc = S;
    #pragma unroll
    for (int s = 0; s < 6; ++s) {
        const int o = 1 << s;
        const float y = __shfl_up(cinc, o, 64);
        if (lane >= o) cinc = fmaf(Fp[s], y, cinc);
    }
    if (lane == 63) sWaveTot[wv] = cinc;
    __syncthreads();
    if (tid == 0) {
        // A^1024 underflows fp32 -> cross-wave decay factor is exactly 0
        float g = 0.0f;
        #pragma unroll
        for (int w = 0; w < 4; ++w) { sCarry[w] = g; g = sWaveTot[w]; }
    }
    __syncthreads();
    const float cprev = __shfl_up(cinc, 1, 64);
    const float Vin = (lane ? cprev : 0.0f)
                    + expf(-3.2f * (float)lane) * sCarry[wv];

    // --- replay chunk with true incoming V; first threshold crossing ---
    float V = Vin;
    int firstT = T_LEN;
    #pragma unroll
    for (int tt = 0; tt < 16; ++tt) {
        V = A * V + OMA * d[tt];
        if (V >= 1.0f && firstT == T_LEN) firstT = 16 * tid + tt;
    }

    // --- block min-reduce ---
    #pragma unroll
    for (int o = 32; o > 0; o >>= 1)
        firstT = min(firstT, __shfl_xor(firstT, o, 64));
    if (lane == 0) sMin[wv] = firstT;
    __syncthreads();
    if (tid == 0) {
        const int f = min(min(sMin[0], sMin[1]), min(sMin[2], sMin[3]));
        const float lat   = (float)f;                          // T if never fired
        const float scale = fmaxf(latency_scale[0], 0.001f);
        out_lat[blk] = lat;
        out_act[blk] = expf(-lat / scale);
        __threadfence();                    // release lat/act to device scope
        const int old = atomicAdd(counter, 1);
        sIsLast = (old == 2047) ? 1 : 0;
    }
    __syncthreads();
    if (!sIsLast) return;

    // ======================= MLP tail (last block only) =====================
    __threadfence();                        // acquire all blocks' act writes
    __shared__ float sAct[2048];            // (8,256)
    __shared__ float sMix[2048];            // (8,256)
    __shared__ float sH[1024];              // (8,128)
    for (int t = tid; t < 2048; t += 256) sAct[t] = out_act[t];
    __syncthreads();

    const int j = tid;
    // mixed[b,j] = bias[j] + sum_i act[b,i] * og[j,i]  (og row read once)
    {
        float mix[8];
        #pragma unroll
        for (int bb = 0; bb < 8; ++bb) mix[bb] = bias[j];
        const float* ogr = og + (size_t)j * 256;
        for (int i = 0; i < 256; ++i) {
            const float w = ogr[i];
            #pragma unroll
            for (int bb = 0; bb < 8; ++bb)
                mix[bb] = fmaf(sAct[bb * 256 + i], w, mix[bb]);
        }
        #pragma unroll
        for (int bb = 0; bb < 8; ++bb) sMix[bb * 256 + j] = mix[bb];
    }
    __syncthreads();

    // h[b,j] = relu(b1[j] + sum_i mixed[b,i] * W1[i,j]) ; W1 (256,128) row-major
    if (j < 128) {
        float h[8];
        #pragma unroll
        for (int bb = 0; bb < 8; ++bb) h[bb] = b1[j];
        for (int i = 0; i < 256; ++i) {
            const float w = W1[i * 128 + j];
            #pragma unroll
            for (int bb = 0; bb < 8; ++bb)
                h[bb] = fmaf(sMix[bb * 256 + i], w, h[bb]);
        }
        #pragma unroll
        for (int bb = 0; bb < 8; ++bb) sH[bb * 128 + j] = fmaxf(h[bb], 0.0f);
    }
    __syncthreads();

    // raw[b,j] = b2[j] + sum_k h[b,k] * W2[k,j] ; W2 (128,256) row-major
    {
        float raw[8];
        #pragma unroll
        for (int bb = 0; bb < 8; ++bb) raw[bb] = b2[j];
        for (int k = 0; k < 128; ++k) {
            const float w = W2[k * 256 + j];
            #pragma unroll
            for (int bb = 0; bb < 8; ++bb)
                raw[bb] = fmaf(sH[bb * 128 + k], w, raw[bb]);
        }
        #pragma unroll
        for (int bb = 0; bb < 8; ++bb) {
            const float r = raw[bb];
            const float sp = fmaxf(r, 0.0f) + log1pf(expf(-fabsf(r)));
            out_pred[bb * 256 + j] = fminf(fmaxf(sp, 0.0f), 4096.0f);
        }
    }
}

// ---------------------------------------------------------------------------
extern "C" void kernel_launch(void* const* d_in, const int* in_sizes, int n_in,
                              void* d_out, int out_size, void* d_ws, size_t ws_size,
                              hipStream_t stream) {
    const float* x    = (const float*)d_in[0];
    const float* w3   = (const float*)d_in[1];
    const float* b3   = (const float*)d_in[2];
    const float* w5   = (const float*)d_in[3];
    const float* b5   = (const float*)d_in[4];
    const float* w9   = (const float*)d_in[5];
    const float* b9   = (const float*)d_in[6];
    const float* wred = (const float*)d_in[7];
    const float* bred = (const float*)d_in[8];
    const float* ls   = (const float*)d_in[9];
    const float* og   = (const float*)d_in[10];
    const float* bias = (const float*)d_in[11];
    const float* W1   = (const float*)d_in[12];
    const float* b1   = (const float*)d_in[13];
    const float* W2   = (const float*)d_in[14];
    const float* b2   = (const float*)d_in[15];

    float* ws       = (float*)d_ws;     // 32 KB folded weights + counter
    int*   counter  = ((int*)d_ws) + 8192;
    float* out      = (float*)d_out;
    float* out_pred = out;              // (8,256)
    float* out_lat  = out + 2048;       // (8,256)
    float* out_act  = out + 4096;       // (8,256)

    fold_kernel<<<1, 256, 0, stream>>>(w3, b3, w5, b5, w9, b9, wred, bred, ws);
    fused_kernel<<<2048, 256, 0, stream>>>(x, ws, ls, og, bias, W1, b1, W2, b2,
                                           out_pred, out_lat, out_act, counter);
}